// Round 1
// baseline (231.876 us; speedup 1.0000x reference)
//
#include <hip/hip_runtime.h>
#include <math.h>

#define NUM_CODE 20000
#define EMBED_D  256
#define HID      128
#define CC       64     // codes per (b,v) row
#define NBV      3200   // 64 * 50

// ---------------------------------------------------------------------------
// Kernel 1: scores[j] = W2 . tanh(W1 @ table[j] + b1) + b2   for j in [0,20000)
// Tiled f32 GEMM (M=20000, N=128, K=256) with fused tanh + W2-dot epilogue.
// Block: 256 threads; M-tile = 64 rows; K staged in 64-wide chunks.
// ---------------------------------------------------------------------------
#define KB   64
#define STR  (KB + 4)   // 68-float LDS stride: breaks bank conflicts, keeps 16B align

__global__ __launch_bounds__(256) void score_kernel(
    const float* __restrict__ table, const float* __restrict__ W1,
    const float* __restrict__ b1, const float* __restrict__ W2,
    const float* __restrict__ b2, float* __restrict__ scores)
{
    __shared__ float Xs[64 * STR];    // 17408 B
    __shared__ float Ws[HID * STR];   // 34816 B  (total 52224 B -> 3 blocks/CU)

    const int tid = threadIdx.x;
    const int tx  = tid & 15;    // N: n = tx*8 + j
    const int ty  = tid >> 4;    // M: m = ty*4 + i
    const int m0  = blockIdx.x * 64;

    float acc[4][8];
#pragma unroll
    for (int i = 0; i < 4; i++)
#pragma unroll
        for (int j = 0; j < 8; j++) acc[i][j] = 0.f;

    for (int k0 = 0; k0 < EMBED_D; k0 += KB) {
        __syncthreads();
        // stage X tile: 64 rows x 64 cols = 1024 float4 (4 per thread)
#pragma unroll
        for (int r = 0; r < 4; r++) {
            int flat = tid + 256 * r;
            int row  = flat >> 4;
            int c4   = flat & 15;
            int gm   = m0 + row;
            float4 v = make_float4(0.f, 0.f, 0.f, 0.f);
            if (gm < NUM_CODE)
                v = *(const float4*)&table[(size_t)gm * EMBED_D + k0 + c4 * 4];
            *(float4*)&Xs[row * STR + c4 * 4] = v;
        }
        // stage W1 tile: 128 rows x 64 cols = 2048 float4 (8 per thread)
#pragma unroll
        for (int r = 0; r < 8; r++) {
            int flat = tid + 256 * r;
            int row  = flat >> 4;
            int c4   = flat & 15;
            float4 v = *(const float4*)&W1[row * EMBED_D + k0 + c4 * 4];
            *(float4*)&Ws[row * STR + c4 * 4] = v;
        }
        __syncthreads();
#pragma unroll
        for (int k4 = 0; k4 < KB / 4; k4++) {
            float4 xv[4], wv[8];
#pragma unroll
            for (int i = 0; i < 4; i++)
                xv[i] = *(const float4*)&Xs[(ty * 4 + i) * STR + k4 * 4];
#pragma unroll
            for (int j = 0; j < 8; j++)
                wv[j] = *(const float4*)&Ws[(tx * 8 + j) * STR + k4 * 4];
#pragma unroll
            for (int i = 0; i < 4; i++)
#pragma unroll
                for (int j = 0; j < 8; j++)
                    acc[i][j] += xv[i].x * wv[j].x + xv[i].y * wv[j].y
                               + xv[i].z * wv[j].z + xv[i].w * wv[j].w;
        }
    }

    // epilogue: h = tanh(acc + b1[n]); partial[i] = sum_n W2[n]*h
    float part[4] = {0.f, 0.f, 0.f, 0.f};
#pragma unroll
    for (int j = 0; j < 8; j++) {
        int n = tx * 8 + j;
        float w2 = W2[n];
        float bb = b1[n];
#pragma unroll
        for (int i = 0; i < 4; i++)
            part[i] += w2 * tanhf(acc[i][j] + bb);
    }

    __syncthreads();                 // done reading Xs -> reuse as reduction buf
    float* red = Xs;                 // need 64*17 floats = 4352 B, fits
#pragma unroll
    for (int i = 0; i < 4; i++)
        red[(ty * 4 + i) * 17 + tx] = part[i];
    __syncthreads();
    if (tid < 64) {
        float s = b2[0];
#pragma unroll
        for (int t = 0; t < 16; t++) s += red[tid * 17 + t];
        int gm = m0 + tid;
        if (gm < NUM_CODE) scores[gm] = s;
    }
}

// ---------------------------------------------------------------------------
// Kernel 2: per (b,v) row — gather scores, masked softmax over C=64,
// attention-weighted sum of embeddings. One block per row, 256 threads.
// ---------------------------------------------------------------------------
__global__ __launch_bounds__(256) void attn_kernel(
    const int* __restrict__ codes, const int* __restrict__ lens,
    const float* __restrict__ table, const float* __restrict__ scores,
    float* __restrict__ out)
{
    __shared__ float attn_s[CC];
    __shared__ int   code_s[CC];
    __shared__ float4 red4[3][64];

    const int bv  = blockIdx.x;
    const int tid = threadIdx.x;

    if (tid < CC) {
        int c = codes[(size_t)bv * CC + tid];
        code_s[tid] = c;
        float sc  = scores[c];
        int   len = lens[bv];
        float val = (tid < len) ? sc : -1e9f;
        float m = val;
#pragma unroll
        for (int o = 32; o >= 1; o >>= 1)
            m = fmaxf(m, __shfl_xor(m, o, 64));
        float e = expf(val - m);
        float sum = e;
#pragma unroll
        for (int o = 32; o >= 1; o >>= 1)
            sum += __shfl_xor(sum, o, 64);
        attn_s[tid] = e / sum;
    }
    __syncthreads();

    const int g = tid >> 6;      // c-group 0..3
    const int l = tid & 63;      // float4 index within D (d = 4l..4l+3)
    const float4* t4 = (const float4*)table;
    float4 acc = make_float4(0.f, 0.f, 0.f, 0.f);
#pragma unroll
    for (int cc = 0; cc < 16; cc++) {
        int c   = cc * 4 + g;
        float a = attn_s[c];
        float4 v = t4[(size_t)code_s[c] * 64 + l];
        acc.x += a * v.x; acc.y += a * v.y; acc.z += a * v.z; acc.w += a * v.w;
    }
    if (g > 0) red4[g - 1][l] = acc;
    __syncthreads();
    if (g == 0) {
#pragma unroll
        for (int r = 0; r < 3; r++) {
            float4 v = red4[r][l];
            acc.x += v.x; acc.y += v.y; acc.z += v.z; acc.w += v.w;
        }
        ((float4*)out)[(size_t)bv * 64 + l] = acc;
    }
}

extern "C" void kernel_launch(void* const* d_in, const int* in_sizes, int n_in,
                              void* d_out, int out_size, void* d_ws, size_t ws_size,
                              hipStream_t stream) {
    const int*   input_code = (const int*)d_in[0];    // [64,50,64] int32
    const int*   length_code = (const int*)d_in[1];   // [64,50]    int32
    const float* embed_table = (const float*)d_in[2]; // [20000,256]
    const float* W1 = (const float*)d_in[3];          // [128,256]
    const float* b1 = (const float*)d_in[4];          // [128]
    const float* W2 = (const float*)d_in[5];          // [1,128]
    const float* b2 = (const float*)d_in[6];          // [1]
    float* out = (float*)d_out;                       // [64,50,256]
    float* scores = (float*)d_ws;                     // 20000 floats scratch

    int grid1 = (NUM_CODE + 63) / 64;                 // 313
    score_kernel<<<grid1, 256, 0, stream>>>(embed_table, W1, b1, W2, b2, scores);
    attn_kernel<<<NBV, 256, 0, stream>>>(input_code, length_code, embed_table,
                                         scores, out);
}

// Round 2
// 165.909 us; speedup vs baseline: 1.3976x; 1.3976x over previous
//
#include <hip/hip_runtime.h>
#include <math.h>

#define NUM_CODE 20000
#define EMBED_D  256
#define HID      128
#define CC       64     // codes per (b,v) row
#define NBV      3200   // 64 * 50
#define KB       64     // K chunk
#define STR      68     // LDS row stride (floats): 68 mod 32 = 4 -> conflict-free interleaved reads

__device__ __forceinline__ unsigned short f2bf(float f) {
    union { float f; unsigned u; } c; c.f = f;
    unsigned r = c.u + 0x7FFFu + ((c.u >> 16) & 1u);   // RNE
    return (unsigned short)(r >> 16);
}
__device__ __forceinline__ float bf2f(unsigned short h) {
    union { unsigned u; float f; } c; c.u = ((unsigned)h) << 16; return c.f;
}

// ---------------------------------------------------------------------------
// Kernel 1: scores[j] = W2 . tanh(W1 @ table[j] + b1) + b2, j in [0,20000)
// M-tile=32 (grid 625), N=128, K chunked by 64. 256 threads.
// n-mapping INTERLEAVED (n = tx + 16*j) so Ws reads have tx-stride 68 ≡ 4
// (mod 32) -> 2-way bank aliasing (free) instead of 16-way conflict.
// Optionally emits a bf16 copy of the table (fused: we read it anyway).
// ---------------------------------------------------------------------------
__global__ __launch_bounds__(256) void score_kernel(
    const float* __restrict__ table, const float* __restrict__ W1,
    const float* __restrict__ b1, const float* __restrict__ W2,
    const float* __restrict__ b2, float* __restrict__ scores,
    unsigned short* __restrict__ tbl_bf, int write_bf)
{
    __shared__ float Xs[32 * STR];    //  8704 B
    __shared__ float Ws[HID * STR];   // 34816 B (total 43.5 KB -> 3 blocks/CU)

    const int tid = threadIdx.x;
    const int tx  = tid & 15;    // n = tx + 16*j
    const int ty  = tid >> 4;    // m = ty*2 + i
    const int m0  = blockIdx.x * 32;   // 625*32 = 20000 exactly, no OOB

    float acc[2][8];
#pragma unroll
    for (int i = 0; i < 2; i++)
#pragma unroll
        for (int j = 0; j < 8; j++) acc[i][j] = 0.f;

    for (int k0 = 0; k0 < EMBED_D; k0 += KB) {
        __syncthreads();
        // stage X: 32 rows x 16 float4 = 512 -> 2 per thread (coalesced)
#pragma unroll
        for (int r = 0; r < 2; r++) {
            int flat = tid + 256 * r;
            int row  = flat >> 4;
            int c4   = flat & 15;
            float4 v = *(const float4*)&table[(size_t)(m0 + row) * EMBED_D + k0 + c4 * 4];
            *(float4*)&Xs[row * STR + c4 * 4] = v;
            if (write_bf) {
                ushort4 b;
                b.x = f2bf(v.x); b.y = f2bf(v.y); b.z = f2bf(v.z); b.w = f2bf(v.w);
                ((ushort4*)tbl_bf)[(size_t)(m0 + row) * 64 + (k0 >> 2) + c4] = b;
            }
        }
        // stage W1: 128 rows x 16 float4 = 2048 -> 8 per thread
#pragma unroll
        for (int r = 0; r < 8; r++) {
            int flat = tid + 256 * r;
            int row  = flat >> 4;
            int c4   = flat & 15;
            *(float4*)&Ws[row * STR + c4 * 4] =
                *(const float4*)&W1[row * EMBED_D + k0 + c4 * 4];
        }
        __syncthreads();
#pragma unroll
        for (int k4 = 0; k4 < KB / 4; k4++) {
            float4 xv[2], wv[8];
#pragma unroll
            for (int i = 0; i < 2; i++)
                xv[i] = *(const float4*)&Xs[(ty * 2 + i) * STR + k4 * 4];
#pragma unroll
            for (int j = 0; j < 8; j++)
                wv[j] = *(const float4*)&Ws[(tx + 16 * j) * STR + k4 * 4];
#pragma unroll
            for (int i = 0; i < 2; i++)
#pragma unroll
                for (int j = 0; j < 8; j++)
                    acc[i][j] += xv[i].x * wv[j].x + xv[i].y * wv[j].y
                               + xv[i].z * wv[j].z + xv[i].w * wv[j].w;
        }
    }

    // epilogue: part[i] = sum_n W2[n] * tanh(acc + b1[n])
    float part[2] = {0.f, 0.f};
#pragma unroll
    for (int j = 0; j < 8; j++) {
        int n = tx + 16 * j;
        float w2 = W2[n];
        float bb = b1[n];
#pragma unroll
        for (int i = 0; i < 2; i++)
            part[i] += w2 * tanhf(acc[i][j] + bb);
    }

    __syncthreads();                 // all waves done reading Xs
    float* red = Xs;                 // 32*17 floats
#pragma unroll
    for (int i = 0; i < 2; i++)
        red[(ty * 2 + i) * 17 + tx] = part[i];
    __syncthreads();
    if (tid < 32) {
        float s = b2[0];
#pragma unroll
        for (int t = 0; t < 16; t++) s += red[tid * 17 + t];
        scores[m0 + tid] = s;
    }
}

// ---------------------------------------------------------------------------
// Kernel 2 (bf16 table): per (b,v) row — masked softmax over C=64 scores,
// attention-weighted sum of bf16 embeddings, f32 accumulate.
// ---------------------------------------------------------------------------
__global__ __launch_bounds__(256) void attn_kernel_bf(
    const int* __restrict__ codes, const int* __restrict__ lens,
    const unsigned short* __restrict__ tbl, const float* __restrict__ scores,
    float* __restrict__ out)
{
    __shared__ float attn_s[CC];
    __shared__ int   code_s[CC];
    __shared__ float4 red4[3][64];

    const int bv  = blockIdx.x;
    const int tid = threadIdx.x;

    if (tid < CC) {
        int c = codes[(size_t)bv * CC + tid];
        code_s[tid] = c;
        float sc  = scores[c];
        int   len = lens[bv];
        float val = (tid < len) ? sc : -1e9f;
        float m = val;
#pragma unroll
        for (int o = 32; o >= 1; o >>= 1)
            m = fmaxf(m, __shfl_xor(m, o, 64));
        float e = expf(val - m);
        float sum = e;
#pragma unroll
        for (int o = 32; o >= 1; o >>= 1)
            sum += __shfl_xor(sum, o, 64);
        attn_s[tid] = e / sum;
    }
    __syncthreads();

    const int g = tid >> 6;      // c-group 0..3
    const int l = tid & 63;      // ushort4 index within D (4 bf16 per lane)
    const ushort4* t4 = (const ushort4*)tbl;
    float4 acc = make_float4(0.f, 0.f, 0.f, 0.f);
#pragma unroll
    for (int cc = 0; cc < 16; cc++) {
        int c   = cc * 4 + g;
        float a = attn_s[c];
        ushort4 q = t4[(size_t)code_s[c] * 64 + l];
        acc.x += a * bf2f(q.x); acc.y += a * bf2f(q.y);
        acc.z += a * bf2f(q.z); acc.w += a * bf2f(q.w);
    }
    if (g > 0) red4[g - 1][l] = acc;
    __syncthreads();
    if (g == 0) {
#pragma unroll
        for (int r = 0; r < 3; r++) {
            float4 v = red4[r][l];
            acc.x += v.x; acc.y += v.y; acc.z += v.z; acc.w += v.w;
        }
        ((float4*)out)[(size_t)bv * 64 + l] = acc;
    }
}

// f32 fallback (used only if d_ws is too small for the bf16 table copy)
__global__ __launch_bounds__(256) void attn_kernel_f32(
    const int* __restrict__ codes, const int* __restrict__ lens,
    const float* __restrict__ table, const float* __restrict__ scores,
    float* __restrict__ out)
{
    __shared__ float attn_s[CC];
    __shared__ int   code_s[CC];
    __shared__ float4 red4[3][64];

    const int bv  = blockIdx.x;
    const int tid = threadIdx.x;

    if (tid < CC) {
        int c = codes[(size_t)bv * CC + tid];
        code_s[tid] = c;
        float sc  = scores[c];
        int   len = lens[bv];
        float val = (tid < len) ? sc : -1e9f;
        float m = val;
#pragma unroll
        for (int o = 32; o >= 1; o >>= 1)
            m = fmaxf(m, __shfl_xor(m, o, 64));
        float e = expf(val - m);
        float sum = e;
#pragma unroll
        for (int o = 32; o >= 1; o >>= 1)
            sum += __shfl_xor(sum, o, 64);
        attn_s[tid] = e / sum;
    }
    __syncthreads();

    const int g = tid >> 6;
    const int l = tid & 63;
    const float4* t4 = (const float4*)table;
    float4 acc = make_float4(0.f, 0.f, 0.f, 0.f);
#pragma unroll
    for (int cc = 0; cc < 16; cc++) {
        int c   = cc * 4 + g;
        float a = attn_s[c];
        float4 v = t4[(size_t)code_s[c] * 64 + l];
        acc.x += a * v.x; acc.y += a * v.y; acc.z += a * v.z; acc.w += a * v.w;
    }
    if (g > 0) red4[g - 1][l] = acc;
    __syncthreads();
    if (g == 0) {
#pragma unroll
        for (int r = 0; r < 3; r++) {
            float4 v = red4[r][l];
            acc.x += v.x; acc.y += v.y; acc.z += v.z; acc.w += v.w;
        }
        ((float4*)out)[(size_t)bv * 64 + l] = acc;
    }
}

extern "C" void kernel_launch(void* const* d_in, const int* in_sizes, int n_in,
                              void* d_out, int out_size, void* d_ws, size_t ws_size,
                              hipStream_t stream) {
    const int*   input_code  = (const int*)d_in[0];   // [64,50,64]
    const int*   length_code = (const int*)d_in[1];   // [64,50]
    const float* embed_table = (const float*)d_in[2]; // [20000,256]
    const float* W1 = (const float*)d_in[3];          // [128,256]
    const float* b1 = (const float*)d_in[4];          // [128]
    const float* W2 = (const float*)d_in[5];          // [1,128]
    const float* b2 = (const float*)d_in[6];          // [1]
    float* out = (float*)d_out;                       // [64,50,256]

    float* scores = (float*)d_ws;                                    // 80 KB
    unsigned short* tbl_bf = (unsigned short*)((char*)d_ws + 81920); // 10.24 MB
    const size_t need = 81920 + (size_t)NUM_CODE * EMBED_D * 2;
    const int use_bf = (ws_size >= need) ? 1 : 0;

    score_kernel<<<NUM_CODE / 32, 256, 0, stream>>>(
        embed_table, W1, b1, W2, b2, scores, tbl_bf, use_bf);
    if (use_bf)
        attn_kernel_bf<<<NBV, 256, 0, stream>>>(input_code, length_code,
                                                tbl_bf, scores, out);
    else
        attn_kernel_f32<<<NBV, 256, 0, stream>>>(input_code, length_code,
                                                 embed_table, scores, out);
}

// Round 3
// 109.666 us; speedup vs baseline: 2.1144x; 1.5129x over previous
//
#include <hip/hip_runtime.h>
#include <math.h>

#define NUM_CODE 20000
#define EMBED_D  256
#define HID      128
#define CC       64
#define NBV      3200

typedef __attribute__((ext_vector_type(8))) short bf16x8;
typedef __attribute__((ext_vector_type(4))) float f32x4;

__device__ __forceinline__ unsigned f2bf1(float f) {
    union { float f; unsigned u; } c; c.f = f;
    return (c.u + 0x7FFFu + ((c.u >> 16) & 1u)) >> 16;   // RNE, as u32
}
__device__ __forceinline__ unsigned pk2(float lo, float hi) {
    return f2bf1(lo) | (f2bf1(hi) << 16);
}
__device__ __forceinline__ float bflo(unsigned u) {
    union { unsigned u; float f; } c; c.u = u << 16; return c.f;
}
__device__ __forceinline__ float bfhi(unsigned u) {
    union { unsigned u; float f; } c; c.u = u & 0xFFFF0000u; return c.f;
}

// ---------------------------------------------------------------------------
// Kernel 0: W1 f32[128][256] -> bf16 (row-major, same linear layout).
// 32 blocks x 256 threads x 1 float4 each = 8192 float4.
// ---------------------------------------------------------------------------
__global__ __launch_bounds__(256) void w1_cvt(
    const float* __restrict__ W1, unsigned short* __restrict__ W1b)
{
    int f = blockIdx.x * 256 + threadIdx.x;
    float4 v = ((const float4*)W1)[f];
    uint2 o; o.x = pk2(v.x, v.y); o.y = pk2(v.z, v.w);
    ((uint2*)W1b)[f] = o;
}

// ---------------------------------------------------------------------------
// Kernel 1: scores[m] = W2 . tanh(W1 @ table[m] + b1) + b2 via bf16 MFMA.
// One wave per 16-row M-tile; grid 1250 x 64 threads. No LDS.
// A frag: lane l holds row=l&15, k=(l>>4)*8+j (contiguous 8) from table f32,
// converted to bf16 in-reg (and stored to tbl_bf — fused table conversion).
// B frag: W1b[n][k] row-major == B^T, bf16x8 contiguous-k load (L2-resident).
// C layout (m89-verified): m=(l>>4)*4+r, n=l&15.
// ---------------------------------------------------------------------------
__global__ __launch_bounds__(64) void score_mfma(
    const float* __restrict__ table, const unsigned short* __restrict__ W1b,
    const float* __restrict__ b1, const float* __restrict__ W2,
    const float* __restrict__ b2, float* __restrict__ scores,
    unsigned short* __restrict__ tbl_bf, int write_bf)
{
    const int l   = threadIdx.x;
    const int row = l & 15;
    const int kg  = l >> 4;
    const int m0  = blockIdx.x * 16;
    const float* arow = table + (size_t)(m0 + row) * EMBED_D + kg * 8;

    f32x4 acc[8];
#pragma unroll
    for (int j = 0; j < 8; j++) acc[j] = (f32x4){0.f, 0.f, 0.f, 0.f};

    float4 a0 = *(const float4*)(arow);
    float4 a1 = *(const float4*)(arow + 4);

#pragma unroll
    for (int s = 0; s < 8; s++) {
        float4 n0, n1;
        if (s < 7) {
            n0 = *(const float4*)(arow + (s + 1) * 32);
            n1 = *(const float4*)(arow + (s + 1) * 32 + 4);
        }
        union { uint4 u; bf16x8 v; } p;
        p.u.x = pk2(a0.x, a0.y); p.u.y = pk2(a0.z, a0.w);
        p.u.z = pk2(a1.x, a1.y); p.u.w = pk2(a1.z, a1.w);
        if (write_bf)
            *(uint4*)(tbl_bf + (size_t)(m0 + row) * EMBED_D + s * 32 + kg * 8) = p.u;
#pragma unroll
        for (int j = 0; j < 8; j++) {
            bf16x8 bf = *(const bf16x8*)(W1b + (size_t)(j * 16 + row) * EMBED_D + s * 32 + kg * 8);
            acc[j] = __builtin_amdgcn_mfma_f32_16x16x32_bf16(p.v, bf, acc[j], 0, 0, 0);
        }
        a0 = n0; a1 = n1;
    }

    // epilogue: this lane's n = row (l&15) for tiles n = j*16+row; m = (l>>4)*4+r
    float w2v[8], b1v[8];
#pragma unroll
    for (int j = 0; j < 8; j++) {
        w2v[j] = W2[j * 16 + row];
        b1v[j] = b1[j * 16 + row];
    }
#pragma unroll
    for (int r = 0; r < 4; r++) {
        float part = 0.f;
#pragma unroll
        for (int j = 0; j < 8; j++)
            part += w2v[j] * tanhf(acc[j][r] + b1v[j]);
#pragma unroll
        for (int o = 1; o < 16; o <<= 1)
            part += __shfl_xor(part, o, 16);
        if (row == 0)
            scores[m0 + kg * 4 + r] = part + b2[0];
    }
}

// ---------------------------------------------------------------------------
// Kernel 2 (bf16): per (b,v) row — masked softmax over 64 scores, weighted
// sum of bf16 embeddings. 8 groups x 32 lanes, dwordx4 gathers (8/thread),
// embedding gathers issued BEFORE softmax (only need code_s).
// ---------------------------------------------------------------------------
__global__ __launch_bounds__(256) void attn_v3(
    const int* __restrict__ codes, const int* __restrict__ lens,
    const uint4* __restrict__ t16, const float* __restrict__ scores,
    float* __restrict__ out)
{
    __shared__ float attn_s[CC];
    __shared__ int   code_s[CC];
    __shared__ float red[8][256];

    const int bv  = blockIdx.x;
    const int tid = threadIdx.x;
    const int g   = tid >> 5;
    const int l   = tid & 31;

    int c_reg = 0;
    if (tid < CC) {
        c_reg = codes[(size_t)bv * CC + tid];
        code_s[tid] = c_reg;
    }
    __syncthreads();

    // issue all embedding gathers (depend only on code_s)
    uint4 v[8];
#pragma unroll
    for (int cc = 0; cc < 8; cc++)
        v[cc] = t16[(size_t)code_s[cc * 8 + g] * 32 + l];

    // softmax on wave 0 (overlaps with gathers in flight)
    if (tid < CC) {
        float sc  = scores[c_reg];
        int   len = lens[bv];
        float val = (tid < len) ? sc : -1e9f;
        float m = val;
#pragma unroll
        for (int o = 32; o >= 1; o >>= 1)
            m = fmaxf(m, __shfl_xor(m, o, 64));
        float e = expf(val - m);
        float sum = e;
#pragma unroll
        for (int o = 32; o >= 1; o >>= 1)
            sum += __shfl_xor(sum, o, 64);
        attn_s[tid] = e / sum;
    }
    __syncthreads();

    float acc[8] = {0.f, 0.f, 0.f, 0.f, 0.f, 0.f, 0.f, 0.f};
#pragma unroll
    for (int cc = 0; cc < 8; cc++) {
        float a = attn_s[cc * 8 + g];
        unsigned u;
        u = v[cc].x; acc[0] += a * bflo(u); acc[1] += a * bfhi(u);
        u = v[cc].y; acc[2] += a * bflo(u); acc[3] += a * bfhi(u);
        u = v[cc].z; acc[4] += a * bflo(u); acc[5] += a * bfhi(u);
        u = v[cc].w; acc[6] += a * bflo(u); acc[7] += a * bfhi(u);
    }
#pragma unroll
    for (int e = 0; e < 8; e++) red[g][l * 8 + e] = acc[e];
    __syncthreads();

    if (tid < 64) {
        float4 o = make_float4(0.f, 0.f, 0.f, 0.f);
#pragma unroll
        for (int g2 = 0; g2 < 8; g2++) {
            float4 r = *(const float4*)&red[g2][tid * 4];
            o.x += r.x; o.y += r.y; o.z += r.z; o.w += r.w;
        }
        ((float4*)out)[(size_t)bv * 64 + tid] = o;
    }
}

// f32 fallback attn (only if d_ws can't hold the bf16 table)
__global__ __launch_bounds__(256) void attn_f32(
    const int* __restrict__ codes, const int* __restrict__ lens,
    const float* __restrict__ table, const float* __restrict__ scores,
    float* __restrict__ out)
{
    __shared__ float attn_s[CC];
    __shared__ int   code_s[CC];
    __shared__ float4 red4[3][64];

    const int bv  = blockIdx.x;
    const int tid = threadIdx.x;

    if (tid < CC) {
        int c = codes[(size_t)bv * CC + tid];
        code_s[tid] = c;
        float sc  = scores[c];
        int   len = lens[bv];
        float val = (tid < len) ? sc : -1e9f;
        float m = val;
#pragma unroll
        for (int o = 32; o >= 1; o >>= 1)
            m = fmaxf(m, __shfl_xor(m, o, 64));
        float e = expf(val - m);
        float sum = e;
#pragma unroll
        for (int o = 32; o >= 1; o >>= 1)
            sum += __shfl_xor(sum, o, 64);
        attn_s[tid] = e / sum;
    }
    __syncthreads();

    const int g = tid >> 6;
    const int l = tid & 63;
    const float4* t4 = (const float4*)table;
    float4 acc = make_float4(0.f, 0.f, 0.f, 0.f);
#pragma unroll
    for (int cc = 0; cc < 16; cc++) {
        int c   = cc * 4 + g;
        float a = attn_s[c];
        float4 vv = t4[(size_t)code_s[c] * 64 + l];
        acc.x += a * vv.x; acc.y += a * vv.y; acc.z += a * vv.z; acc.w += a * vv.w;
    }
    if (g > 0) red4[g - 1][l] = acc;
    __syncthreads();
    if (g == 0) {
#pragma unroll
        for (int r = 0; r < 3; r++) {
            float4 vv = red4[r][l];
            acc.x += vv.x; acc.y += vv.y; acc.z += vv.z; acc.w += vv.w;
        }
        ((float4*)out)[(size_t)bv * 64 + l] = acc;
    }
}

extern "C" void kernel_launch(void* const* d_in, const int* in_sizes, int n_in,
                              void* d_out, int out_size, void* d_ws, size_t ws_size,
                              hipStream_t stream) {
    const int*   input_code  = (const int*)d_in[0];   // [64,50,64]
    const int*   length_code = (const int*)d_in[1];   // [64,50]
    const float* embed_table = (const float*)d_in[2]; // [20000,256]
    const float* W1 = (const float*)d_in[3];          // [128,256]
    const float* b1 = (const float*)d_in[4];          // [128]
    const float* W2 = (const float*)d_in[5];          // [1,128]
    const float* b2 = (const float*)d_in[6];          // [1]
    float* out = (float*)d_out;                       // [64,50,256]

    // ws layout: scores (80 KB) | W1b (64 KB) | tbl_bf (10.24 MB)
    float*          scores = (float*)d_ws;
    unsigned short* W1b    = (unsigned short*)((char*)d_ws + 81920);
    unsigned short* tbl_bf = (unsigned short*)((char*)d_ws + 81920 + 65536);
    const size_t need_full = 81920 + 65536 + (size_t)NUM_CODE * EMBED_D * 2;
    const int use_bf = (ws_size >= need_full) ? 1 : 0;

    w1_cvt<<<32, 256, 0, stream>>>(W1, W1b);
    score_mfma<<<NUM_CODE / 16, 64, 0, stream>>>(
        embed_table, W1b, b1, W2, b2, scores, tbl_bf, use_bf);
    if (use_bf)
        attn_v3<<<NBV, 256, 0, stream>>>(input_code, length_code,
                                         (const uint4*)tbl_bf, scores, out);
    else
        attn_f32<<<NBV, 256, 0, stream>>>(input_code, length_code,
                                          embed_table, scores, out);
}